// Round 7
// baseline (50.691 us; speedup 1.0000x reference)
//
#include <hip/hip_runtime.h>
#include <hip/hip_bf16.h>

// SoftDP: soft value-iteration backward over H, then softmax over K.
// E: [B=2048, H=64, K=512] f32.  out: [B, K] f32.
//
// Algebra (R3): renormalize each step by log(c*S) instead of max(V):
//   X_k = exp(V_k);  S = sum_k X_k
//   V_k <- -E[b,t,k] + log(1 + X_k/(c*S)),   c = exp(-kappa)
// X_k/(c*S) <= 1/c, so V stays in ~[-6.5, 6.5]: no overflow, no max pass.
// Softmax is shift-invariant so the dropped log(c*S) shifts cancel.
//
// Reduction (R5): xor16 via ds_swizzle (single LDS hop), xor1/2/4/8 via DPP,
// xor32 via permlane32_swap. One wave per row (64 lanes x 8 elems).
//
// R6/R7: nontemporal streaming loads/stores (via native ext_vector_type --
// HIP_vector_type float4 is rejected by the builtin), prefetch depth 4,
// unroll-4 so the prefetch rotation is register renaming instead of moves.

#define BB 2048
#define HH 64
#define KK 512

typedef float f32x4 __attribute__((ext_vector_type(4)));

template <int CTRL>
__device__ __forceinline__ float dpp_add(float v) {
    int s = __builtin_amdgcn_update_dpp(__float_as_int(v), __float_as_int(v),
                                        CTRL, 0xf, 0xf, false);
    return v + __int_as_float(s);
}

__device__ __forceinline__ float wave_sum_fast(float p) {
    float t = __int_as_float(__builtin_amdgcn_ds_swizzle(__float_as_int(p), 0x401F));
    float s = p + t;
    s = dpp_add<0xB1>(s);    // xor1
    s = dpp_add<0x4E>(s);    // xor2
    s = dpp_add<0x141>(s);   // xor4 (row_half_mirror; quads uniform)
    s = dpp_add<0x140>(s);   // xor8 (row_mirror; 8-groups uniform)
    auto pr = __builtin_amdgcn_permlane32_swap(__float_as_int(s),
                                               __float_as_int(s), false, false);
    return __int_as_float(pr[0]) + __int_as_float(pr[1]);  // + xor32
}

__device__ __forceinline__ f32x4 ldnt(const f32x4* p) {
    return __builtin_nontemporal_load(p);
}

__global__ __launch_bounds__(64) void softdp_kernel(
        const float* __restrict__ E, float* __restrict__ out) {
    const int b    = blockIdx.x;
    const int lane = threadIdx.x;

    const f32x4* __restrict__ Erow =
        reinterpret_cast<const f32x4*>(E) + (size_t)b * (HH * KK / 4) + 2 * lane;
    f32x4* __restrict__ Orow =
        reinterpret_cast<f32x4*>(out) + (size_t)b * (KK / 4) + 2 * lane;

    const float c = 0.6065306597126334f;  // exp(-kappa), kappa = 0.5

    float V[8] = {0.f, 0.f, 0.f, 0.f, 0.f, 0.f, 0.f, 0.f};

    // prefetch pipeline depth 4: A=E[t], B=E[t-1], C=E[t-2], D=E[t-3]
    f32x4 eA0 = ldnt(Erow + (HH - 1) * (KK / 4)), eA1 = ldnt(Erow + (HH - 1) * (KK / 4) + 1);
    f32x4 eB0 = ldnt(Erow + (HH - 2) * (KK / 4)), eB1 = ldnt(Erow + (HH - 2) * (KK / 4) + 1);
    f32x4 eC0 = ldnt(Erow + (HH - 3) * (KK / 4)), eC1 = ldnt(Erow + (HH - 3) * (KK / 4) + 1);
    f32x4 eD0 = ldnt(Erow + (HH - 4) * (KK / 4)), eD1 = ldnt(Erow + (HH - 4) * (KK / 4) + 1);

#pragma unroll 4
    for (int t = HH - 1; t >= 0; --t) {
        // issue load of E[t-4] (clamped; tail re-loads hit L1)
        const int tn = (t >= 4) ? (t - 4) : 0;
        f32x4 eE0 = ldnt(Erow + tn * (KK / 4));
        f32x4 eE1 = ldnt(Erow + tn * (KK / 4) + 1);

        // ---- X = exp(V), wave sum (V bounded: no max shift) ----
        float x0 = __expf(V[0]), x1 = __expf(V[1]);
        float x2 = __expf(V[2]), x3 = __expf(V[3]);
        float x4 = __expf(V[4]), x5 = __expf(V[5]);
        float x6 = __expf(V[6]), x7 = __expf(V[7]);
        float p = ((x0 + x1) + (x2 + x3)) + ((x4 + x5) + (x6 + x7));
        float s = wave_sum_fast(p);

        // ---- update, renormalized by log(c*s) ----
        const float r = __builtin_amdgcn_rcpf(c * s);
        V[0] = -eA0[0] + __logf(fmaf(x0, r, 1.0f));
        V[1] = -eA0[1] + __logf(fmaf(x1, r, 1.0f));
        V[2] = -eA0[2] + __logf(fmaf(x2, r, 1.0f));
        V[3] = -eA0[3] + __logf(fmaf(x3, r, 1.0f));
        V[4] = -eA1[0] + __logf(fmaf(x4, r, 1.0f));
        V[5] = -eA1[1] + __logf(fmaf(x5, r, 1.0f));
        V[6] = -eA1[2] + __logf(fmaf(x6, r, 1.0f));
        V[7] = -eA1[3] + __logf(fmaf(x7, r, 1.0f));

        // rotate prefetch pipeline (renamed away under unroll)
        eA0 = eB0; eA1 = eB1;
        eB0 = eC0; eB1 = eC1;
        eC0 = eD0; eC1 = eD1;
        eD0 = eE0; eD1 = eE1;
    }

    // ---- final softmax over K ----
    float x0 = __expf(V[0]), x1 = __expf(V[1]);
    float x2 = __expf(V[2]), x3 = __expf(V[3]);
    float x4 = __expf(V[4]), x5 = __expf(V[5]);
    float x6 = __expf(V[6]), x7 = __expf(V[7]);
    float p = ((x0 + x1) + (x2 + x3)) + ((x4 + x5) + (x6 + x7));
    float s = wave_sum_fast(p);

    const float inv = __builtin_amdgcn_rcpf(s);
    f32x4 o0, o1;
    o0[0] = x0 * inv; o0[1] = x1 * inv; o0[2] = x2 * inv; o0[3] = x3 * inv;
    o1[0] = x4 * inv; o1[1] = x5 * inv; o1[2] = x6 * inv; o1[3] = x7 * inv;
    __builtin_nontemporal_store(o0, Orow);
    __builtin_nontemporal_store(o1, Orow + 1);
}

extern "C" void kernel_launch(void* const* d_in, const int* in_sizes, int n_in,
                              void* d_out, int out_size, void* d_ws, size_t ws_size,
                              hipStream_t stream) {
    const float* E = (const float*)d_in[0];
    float* out = (float*)d_out;
    softdp_kernel<<<dim3(BB), dim3(64), 0, stream>>>(E, out);
}

// Round 8
// 46.767 us; speedup vs baseline: 1.0839x; 1.0839x over previous
//
#include <hip/hip_runtime.h>
#include <hip/hip_bf16.h>

// SoftDP: soft value-iteration backward over H, then softmax over K.
// E: [B=2048, H=64, K=512] f32.  out: [B, K] f32.
//
// Algebra (R3): renormalize each step by log(c*S) instead of max(V):
//   X_k = exp(V_k);  S = sum_k X_k
//   V_k <- -E[b,t,k] + log(1 + X_k/(c*S)),   c = exp(-kappa)
// X_k/(c*S) <= 1/c, so V stays in ~[-6.5, 6.5]: no overflow, no max pass.
// Softmax is shift-invariant so the dropped log(c*S) shifts cancel.
//
// Reduction (R5): xor16 via ds_swizzle (single LDS hop), xor1/2/4/8 via DPP,
// xor32 via permlane32_swap. One wave per row (64 lanes x 8 elems).
//
// R8 = exact revert to R5 (best: 46.7 us, 92.8% of HBM floor). The R6/R7
// bundle (nontemporal + depth-4 + unroll-4) regressed to 50.7 us -- nt
// eviction hints hurt the cached tail re-loads and depth-4 added register
// pressure without covering any additional latency.

#define BB 2048
#define HH 64
#define KK 512

template <int CTRL>
__device__ __forceinline__ float dpp_add(float v) {
    int s = __builtin_amdgcn_update_dpp(__float_as_int(v), __float_as_int(v),
                                        CTRL, 0xf, 0xf, false);
    return v + __int_as_float(s);
}

__device__ __forceinline__ float wave_sum_fast(float p) {
    // xor16 first (the single LDS-latency hop)
    float t = __int_as_float(__builtin_amdgcn_ds_swizzle(__float_as_int(p), 0x401F));
    float s = p + t;
    s = dpp_add<0xB1>(s);    // quad_perm [1,0,3,2]  : xor1
    s = dpp_add<0x4E>(s);    // quad_perm [2,3,0,1]  : xor2
    s = dpp_add<0x141>(s);   // row_half_mirror      : xor4 (quads uniform)
    s = dpp_add<0x140>(s);   // row_mirror           : xor8 (8-groups uniform)
    auto pr = __builtin_amdgcn_permlane32_swap(__float_as_int(s),
                                               __float_as_int(s), false, false);
    return __int_as_float(pr[0]) + __int_as_float(pr[1]);  // + xor32
}

__global__ __launch_bounds__(64) void softdp_kernel(
        const float* __restrict__ E, float* __restrict__ out) {
    const int b    = blockIdx.x;
    const int lane = threadIdx.x;

    const float4* __restrict__ Erow =
        reinterpret_cast<const float4*>(E) + (size_t)b * (HH * KK / 4) + 2 * lane;
    float4* __restrict__ Orow =
        reinterpret_cast<float4*>(out) + (size_t)b * (KK / 4) + 2 * lane;

    const float c = 0.6065306597126334f;  // exp(-kappa), kappa = 0.5

    float V[8] = {0.f, 0.f, 0.f, 0.f, 0.f, 0.f, 0.f, 0.f};

    // prefetch pipeline: A = E[t], B = E[t-1], C = E[t-2]
    float4 eA0 = Erow[(HH - 1) * (KK / 4)], eA1 = Erow[(HH - 1) * (KK / 4) + 1];
    float4 eB0 = Erow[(HH - 2) * (KK / 4)], eB1 = Erow[(HH - 2) * (KK / 4) + 1];
    float4 eC0 = Erow[(HH - 3) * (KK / 4)], eC1 = Erow[(HH - 3) * (KK / 4) + 1];

    for (int t = HH - 1; t >= 0; --t) {
        // issue load of E[t-3] (clamped; tail re-loads hit L1/L2)
        const int tn = (t >= 3) ? (t - 3) : 0;
        float4 eD0 = Erow[tn * (KK / 4)];
        float4 eD1 = Erow[tn * (KK / 4) + 1];

        // ---- X = exp(V), wave sum (V bounded: no max shift) ----
        float x0 = __expf(V[0]), x1 = __expf(V[1]);
        float x2 = __expf(V[2]), x3 = __expf(V[3]);
        float x4 = __expf(V[4]), x5 = __expf(V[5]);
        float x6 = __expf(V[6]), x7 = __expf(V[7]);
        float p = ((x0 + x1) + (x2 + x3)) + ((x4 + x5) + (x6 + x7));
        float s = wave_sum_fast(p);

        // ---- update, renormalized by log(c*s) ----
        const float r = __builtin_amdgcn_rcpf(c * s);
        V[0] = -eA0.x + __logf(fmaf(x0, r, 1.0f));
        V[1] = -eA0.y + __logf(fmaf(x1, r, 1.0f));
        V[2] = -eA0.z + __logf(fmaf(x2, r, 1.0f));
        V[3] = -eA0.w + __logf(fmaf(x3, r, 1.0f));
        V[4] = -eA1.x + __logf(fmaf(x4, r, 1.0f));
        V[5] = -eA1.y + __logf(fmaf(x5, r, 1.0f));
        V[6] = -eA1.z + __logf(fmaf(x6, r, 1.0f));
        V[7] = -eA1.w + __logf(fmaf(x7, r, 1.0f));

        // rotate prefetch pipeline
        eA0 = eB0; eA1 = eB1;
        eB0 = eC0; eB1 = eC1;
        eC0 = eD0; eC1 = eD1;
    }

    // ---- final softmax over K ----
    float x0 = __expf(V[0]), x1 = __expf(V[1]);
    float x2 = __expf(V[2]), x3 = __expf(V[3]);
    float x4 = __expf(V[4]), x5 = __expf(V[5]);
    float x6 = __expf(V[6]), x7 = __expf(V[7]);
    float p = ((x0 + x1) + (x2 + x3)) + ((x4 + x5) + (x6 + x7));
    float s = wave_sum_fast(p);

    const float inv = __builtin_amdgcn_rcpf(s);
    float4 o0, o1;
    o0.x = x0 * inv; o0.y = x1 * inv; o0.z = x2 * inv; o0.w = x3 * inv;
    o1.x = x4 * inv; o1.y = x5 * inv; o1.z = x6 * inv; o1.w = x7 * inv;
    Orow[0] = o0;
    Orow[1] = o1;
}

extern "C" void kernel_launch(void* const* d_in, const int* in_sizes, int n_in,
                              void* d_out, int out_size, void* d_ws, size_t ws_size,
                              hipStream_t stream) {
    const float* E = (const float*)d_in[0];
    float* out = (float*)d_out;
    softdp_kernel<<<dim3(BB), dim3(64), 0, stream>>>(E, out);
}